// Round 1
// baseline (668.406 us; speedup 1.0000x reference)
//
#include <hip/hip_runtime.h>

// Problem constants (match setup_inputs)
#define BS 256
#define NQ 512
#define NC 128
#define NP 256
#define NG 128
#define TQ 32            // queries per block in main kernel

__device__ __forceinline__ float wave_max(float v) {
    for (int off = 32; off >= 1; off >>= 1) v = fmaxf(v, __shfl_xor(v, off, 64));
    return v;
}
__device__ __forceinline__ float wave_sum(float v) {
    for (int off = 32; off >= 1; off >>= 1) v += __shfl_xor(v, off, 64);
    return v;
}

// Kernel 1: lse[b*NP+p] = logsumexp over q of att[b,p,:]  (row of 512 contiguous floats)
__global__ __launch_bounds__(256) void lse_kernel(const float* __restrict__ att,
                                                  float* __restrict__ lse) {
    int row  = blockIdx.x * 4 + (threadIdx.x >> 6);   // one wave per row
    int lane = threadIdx.x & 63;
    const float4* a4 = (const float4*)(att + (size_t)row * NQ);
    float4 v0 = a4[lane];        // fully coalesced: 64 lanes x 16B
    float4 v1 = a4[lane + 64];
    float mx = fmaxf(fmaxf(fmaxf(v0.x, v0.y), fmaxf(v0.z, v0.w)),
                     fmaxf(fmaxf(v1.x, v1.y), fmaxf(v1.z, v1.w)));
    mx = wave_max(mx);
    float s = __expf(v0.x - mx) + __expf(v0.y - mx) + __expf(v0.z - mx) + __expf(v0.w - mx)
            + __expf(v1.x - mx) + __expf(v1.y - mx) + __expf(v1.z - mx) + __expf(v1.w - mx);
    s = wave_sum(s);
    if (lane == 0) lse[row] = mx + __logf(s);
}

// Kernel 2: one block per (b, q-tile of TQ). Computes full cost for TQ x NG outputs.
__global__ __launch_bounds__(256) void cost_kernel(
    const float* __restrict__ predAct,   // [BS,NQ,NC]
    const float* __restrict__ att,       // [BS,NP,NQ]
    const int*   __restrict__ actIds,    // [BS,NG]
    const int*   __restrict__ grpIds,    // [BS,NP]
    const float* __restrict__ lseAtt,    // [BS*NP]
    float*       __restrict__ out)       // [BS,NQ,NG]
{
    __shared__ float memLogP[NG * TQ];       // [g][qo]  member-sum of logP
    __shared__ float memL1p [NG * TQ];       // [g][qo]  member-sum of log(1-P)
    __shared__ float actRow [TQ][NC];        // staged activity-logit rows
    __shared__ float lseAct [TQ];
    __shared__ float sumL1p [TQ];            // total over all persons
    __shared__ float predSz [TQ];            // sum_p P_qn
    __shared__ int   gidS[NP];
    __shared__ int   aidS[NG];
    __shared__ int   cntS[NG];

    const int b    = blockIdx.x >> 4;        // NQ/TQ = 16 tiles per batch
    const int q0   = (blockIdx.x & 15) * TQ;
    const int t    = threadIdx.x;

    // ---- init ----
    for (int i = t; i < NG * TQ; i += 256) { memLogP[i] = 0.f; memL1p[i] = 0.f; }
    if (t < NG) { cntS[t] = 0; aidS[t] = actIds[b * NG + t]; }
    if (t < TQ) { sumL1p[t] = 0.f; predSz[t] = 0.f; }
    gidS[t] = grpIds[b * NP + t];
    __syncthreads();
    atomicAdd(&cntS[gidS[t]], 1);

    // ---- activity log-softmax rows (one wave per row) ----
    const int wave = t >> 6, lane = t & 63;
    for (int r = wave; r < TQ; r += 4) {
        const float* rowp = predAct + ((size_t)(b * NQ + q0 + r)) * NC;
        float v0 = rowp[lane], v1 = rowp[lane + 64];
        actRow[r][lane] = v0; actRow[r][lane + 64] = v1;
        float mx = wave_max(fmaxf(v0, v1));
        float s  = wave_sum(__expf(v0 - mx) + __expf(v1 - mx));
        if (lane == 0) lseAct[r] = mx + __logf(s);
    }
    __syncthreads();

    // ---- grouping accumulation over persons ----
    const int qo   = t & 31;      // query offset within tile
    const int psub = t >> 5;      // 8 persons in flight
    float myL1p = 0.f, myPs = 0.f;
    for (int pb = 0; pb < NP; pb += 8) {
        const int p = pb + psub;
        float x  = att[((size_t)(b * NP + p)) * NQ + q0 + qo] - lseAtt[b * NP + p];
        float Pv = __expf(x);
        float Pc = fminf(fmaxf(Pv, 1e-6f), 1.f - 1e-6f);
        float l1p = __logf(1.f - Pc);
        const int g = gidS[p];
        // lanes 0..31 of a wave share p (same g), qo distinct -> conflict-free banks
        atomicAdd(&memLogP[g * TQ + qo], x);
        atomicAdd(&memL1p [g * TQ + qo], l1p);
        myL1p += l1p; myPs += Pv;
    }
    atomicAdd(&sumL1p[qo], myL1p);
    atomicAdd(&predSz[qo], myPs);
    __syncthreads();

    // ---- finalize + coalesced write ----
    for (int rep = 0; rep < TQ * NG / 256; ++rep) {
        const int idx = rep * 256 + t;
        const int qq  = idx >> 7;          // 0..TQ-1
        const int g   = idx & (NG - 1);
        const int m   = cntS[g];
        const float mf  = (float)m;
        const float nmf = (float)(NP - m);
        float grouping = -memLogP[g * TQ + qq] / fmaxf(mf, 1.f)
                         - (sumL1p[qq] - memL1p[g * TQ + qq]) / fmaxf(nmf, 1.f);
        float szc = fabsf(predSz[qq] - mf) * (1.0f / NP);
        if (m == 0) { grouping = 1.0e6f; szc = 1.0e6f; }
        const float actC = lseAct[qq] - actRow[qq][aidS[g]];
        out[((size_t)(b * NQ + q0 + qq)) * NG + g] = grouping + actC + szc;
    }
}

extern "C" void kernel_launch(void* const* d_in, const int* in_sizes, int n_in,
                              void* d_out, int out_size, void* d_ws, size_t ws_size,
                              hipStream_t stream) {
    const float* predAct = (const float*)d_in[0];
    const float* att     = (const float*)d_in[1];
    const int*   actIds  = (const int*)d_in[2];
    const int*   grpIds  = (const int*)d_in[3];
    float*       out     = (float*)d_out;
    float*       lse     = (float*)d_ws;     // BS*NP floats = 256 KB

    lse_kernel<<<BS * NP / 4, 256, 0, stream>>>(att, lse);
    cost_kernel<<<BS * (NQ / TQ), 256, 0, stream>>>(predAct, att, actIds, grpIds, lse, out);
}

// Round 2
// 341.137 us; speedup vs baseline: 1.9593x; 1.9593x over previous
//
#include <hip/hip_runtime.h>

#define BS 256
#define NQ 512
#define NC 128
#define NP 256
#define NG 128
#define TQ 32
#define BIGC 1.0e6f
#define EPSC 1e-6f

// ---------------- Kernel 1: LSE over queries for attention rows ----------------
// att is [BS, NP, NQ]; one 16-lane sub-group per row of 512 floats.
__global__ __launch_bounds__(256) void lse_kernel(const float* __restrict__ att,
                                                  float* __restrict__ lse) {
    const int t   = threadIdx.x;
    const int row = blockIdx.x * 16 + (t >> 4);
    const int sub = t & 15;
    const float4* a4 = (const float4*)(att + (size_t)row * NQ);
    float4 v[8];
#pragma unroll
    for (int i = 0; i < 8; ++i) v[i] = a4[sub + 16 * i];   // 256B contiguous per 16 lanes
    float mx = -1e30f;
#pragma unroll
    for (int i = 0; i < 8; ++i)
        mx = fmaxf(mx, fmaxf(fmaxf(v[i].x, v[i].y), fmaxf(v[i].z, v[i].w)));
#pragma unroll
    for (int off = 1; off < 16; off <<= 1) mx = fmaxf(mx, __shfl_xor(mx, off, 64));
    float s = 0.f;
#pragma unroll
    for (int i = 0; i < 8; ++i)
        s += __expf(v[i].x - mx) + __expf(v[i].y - mx) + __expf(v[i].z - mx) + __expf(v[i].w - mx);
#pragma unroll
    for (int off = 1; off < 16; off <<= 1) s += __shfl_xor(s, off, 64);
    if (sub == 0) lse[row] = mx + __logf(s);
}

// ---------------- Kernel 2: full cost for a (b, 32-query) tile ----------------
__global__ __launch_bounds__(256) void cost_kernel(
    const float* __restrict__ predAct,   // [BS,NQ,NC]
    const float* __restrict__ att,       // [BS,NP,NQ]
    const int*   __restrict__ actIds,    // [BS,NG]
    const int*   __restrict__ grpIds,    // [BS,NP]
    const float* __restrict__ lseAtt,    // [BS*NP]
    float*       __restrict__ out)       // [BS,NQ,NG]
{
    __shared__ float xS[NP * TQ];        // logP tile [p][qo], 32 KB
    __shared__ float lseS[NP];
    __shared__ float lseAct[TQ];
    __shared__ float sumL1p[TQ];
    __shared__ float predSz[TQ];
    __shared__ int   gidS[NP];
    __shared__ int   memberS[NP];
    __shared__ int   aidS[NG];
    __shared__ int   cntS[NG];
    __shared__ int   startS[NG];
    __shared__ int   scanS[NG];

    const int b  = blockIdx.x >> 4;
    const int q0 = (blockIdx.x & 15) * TQ;
    const int t  = threadIdx.x;

    // ---- init + small staging ----
    lseS[t] = lseAtt[b * NP + t];
    gidS[t] = grpIds[b * NP + t];
    if (t < NG) { aidS[t] = actIds[b * NG + t]; cntS[t] = 0; }
    if (t < TQ) { sumL1p[t] = 0.f; predSz[t] = 0.f; }
    __syncthreads();

    // person t claims a slot in its group's member list (256 LDS atomics total)
    const int myPos = atomicAdd(&cntS[gidS[t]], 1);

    // ---- phase A: stage x = logP tile + per-qo totals ----
    const int pr  = t >> 3;          // person row within 32-row slab
    const int qo4 = (t & 7) * 4;     // float4 query offset
    float pl[4] = {0.f, 0.f, 0.f, 0.f};
    float ps[4] = {0.f, 0.f, 0.f, 0.f};
#pragma unroll
    for (int iter = 0; iter < 8; ++iter) {
        const int p = iter * 32 + pr;
        float4 v = *(const float4*)(att + ((size_t)(b * NP + p)) * NQ + q0 + qo4);
        const float l = lseS[p];
        float xv[4] = {v.x - l, v.y - l, v.z - l, v.w - l};
        *(float4*)(xS + p * TQ + qo4) = *(float4*)xv;
#pragma unroll
        for (int j = 0; j < 4; ++j) {
            float e = __expf(xv[j]);
            ps[j] += e;
            float c = fminf(fmaxf(e, EPSC), 1.f - EPSC);
            pl[j] += __logf(1.f - c);
        }
    }
    // reduce across lanes sharing (lane & 7)
#pragma unroll
    for (int j = 0; j < 4; ++j) {
#pragma unroll
        for (int off = 8; off < 64; off <<= 1) {
            pl[j] += __shfl_xor(pl[j], off, 64);
            ps[j] += __shfl_xor(ps[j], off, 64);
        }
    }
    if ((t & 63) < 8) {
#pragma unroll
        for (int j = 0; j < 4; ++j) {
            atomicAdd(&sumL1p[qo4 + j], pl[j]);
            atomicAdd(&predSz[qo4 + j], ps[j]);
        }
    }

    // ---- phase A2: activity row LSEs (one wave per row, 8 rows/wave) ----
    const int wv = t >> 6, ln = t & 63;
    for (int r = wv; r < TQ; r += 4) {
        const float* rowp = predAct + ((size_t)(b * NQ + q0 + r)) * NC;
        const float v0 = rowp[ln], v1 = rowp[ln + 64];
        float mx = fmaxf(v0, v1);
#pragma unroll
        for (int off = 1; off < 64; off <<= 1) mx = fmaxf(mx, __shfl_xor(mx, off, 64));
        float s = __expf(v0 - mx) + __expf(v1 - mx);
#pragma unroll
        for (int off = 1; off < 64; off <<= 1) s += __shfl_xor(s, off, 64);
        if (ln == 0) lseAct[r] = mx + __logf(s);
    }
    __syncthreads();   // xS, cntS atomics, sums, lseAct all visible

    // ---- phase B: exclusive scan of group counts -> CSR ----
    if (t < NG) scanS[t] = cntS[t];
    __syncthreads();
    for (int off = 1; off < NG; off <<= 1) {
        int v = 0;
        if (t < NG && t >= off) v = scanS[t - off];
        __syncthreads();
        if (t < NG) scanS[t] += v;
        __syncthreads();
    }
    if (t < NG) startS[t] = scanS[t] - cntS[t];
    __syncthreads();
    memberS[startS[gidS[t]] + myPos] = t;
    __syncthreads();

    // ---- phase C: gather per (group, query), 4 groups per thread ----
    const float* actBase = predAct + ((size_t)(b * NQ + q0)) * NC;
#pragma unroll
    for (int rep = 0; rep < 4; ++rep) {
        const int idx = rep * 256 + t;
        const int qo  = idx & 31;          // lane-fast -> conflict-free xS banks
        const int g4  = (idx >> 5) * 4;
        const float sl = sumL1p[qo], pz = predSz[qo], la = lseAct[qo];
        float res[4];
#pragma unroll
        for (int j = 0; j < 4; ++j) {
            const int g  = g4 + j;
            const int m  = cntS[g];
            const int st = startS[g];
            float ms = 0.f, ml = 0.f;
            for (int i = 0; i < m; ++i) {
                const int p = memberS[st + i];          // broadcast (same addr in half-wave)
                const float x = xS[p * TQ + qo];        // banks 0..31, conflict-free
                ms += x;
                const float e = __expf(x);
                const float c = fminf(fmaxf(e, EPSC), 1.f - EPSC);
                ml += __logf(1.f - c);
            }
            const float mf  = (float)m;
            const float nmf = (float)(NP - m);
            float grp = -ms / fmaxf(mf, 1.f) - (sl - ml) / fmaxf(nmf, 1.f);
            float szc = fabsf(pz - mf) * (1.f / (float)NP);
            if (m == 0) { grp = BIGC; szc = BIGC; }
            const float av = actBase[(size_t)qo * NC + aidS[g]];   // L1-hot gather
            res[j] = grp + (la - av) + szc;
        }
        *(float4*)(out + ((size_t)(b * NQ + q0 + qo)) * NG + g4) = *(float4*)res;
    }
}

extern "C" void kernel_launch(void* const* d_in, const int* in_sizes, int n_in,
                              void* d_out, int out_size, void* d_ws, size_t ws_size,
                              hipStream_t stream) {
    const float* predAct = (const float*)d_in[0];
    const float* att     = (const float*)d_in[1];
    const int*   actIds  = (const int*)d_in[2];
    const int*   grpIds  = (const int*)d_in[3];
    float*       out     = (float*)d_out;
    float*       lse     = (float*)d_ws;     // BS*NP floats = 256 KB

    lse_kernel<<<BS * NP / 16, 256, 0, stream>>>(att, lse);
    cost_kernel<<<BS * (NQ / TQ), 256, 0, stream>>>(predAct, att, actIds, grpIds, lse, out);
}